// Round 8
// baseline (567.879 us; speedup 1.0000x reference)
//
#include <hip/hip_runtime.h>
#include <hip/hip_bf16.h>
#include <math.h>

#define BB 32768
#define EE 16
#define HH 128
#define OBS 8
#define NSTEP 19
#define TPB 512
#define MROWS 64
#define KT 5
#define H32S 130
// fragment-order B buffer: elem index of frag (nt, kt, T) start
#define FBX(nt,kt,T) ((((nt)*KT+(kt))*2+(T))*512)

typedef short s16x8 __attribute__((ext_vector_type(8)));   // 8 bf16 = 4 VGPRs (MFMA A/B frag)
typedef float f32x4 __attribute__((ext_vector_type(4)));   // MFMA C/D frag

__device__ __forceinline__ float sigm(float x){ return __builtin_amdgcn_rcpf(1.0f + __expf(-x)); }
__device__ __forceinline__ float ftanh(float x){ float e = __expf(-2.f*x); return (1.f-e)*__builtin_amdgcn_rcpf(1.f+e); }
__device__ __forceinline__ unsigned int f2b(float x){
    __hip_bfloat16 h = __float2bfloat16(x);
    return (unsigned int)*reinterpret_cast<unsigned short*>(&h);
}
__device__ __forceinline__ float b2f_(unsigned int u){ return __uint_as_float(u << 16); }

// Pack W_cat = [W_ih | W_hh] (K=144, pad 160) into MFMA A-frag order, bf16 hi+lo.
// Frag (JT 0..31, kt 0..4): lane l elem j = W_cat[k = kt*32+(l>>4)*8+j][jg = JT*16+(l&15)],
// jg = 4*j_hidden + gate.
__global__ __launch_bounds__(256) void k_prep(
    const float* __restrict__ W_ih, const float* __restrict__ W_hh,
    unsigned short* __restrict__ Whi, unsigned short* __restrict__ Wlo)
{
    int idx = blockIdx.x * 256 + threadIdx.x;      // 32*5*512 = 81920
    int j    = idx & 7;
    int lane = (idx >> 3) & 63;
    int kt   = (idx >> 9) % KT;
    int JT   = idx / (KT * 512);
    int k  = kt * 32 + ((lane >> 4) << 3) + j;
    int jg = JT * 16 + (lane & 15);
    int col = (jg & 3) * HH + (jg >> 2);
    float wv = 0.f;
    if (k < EE)            wv = W_ih[col * EE + k];
    else if (k < EE + HH)  wv = W_hh[col * HH + (k - EE)];
    unsigned int hi = f2b(wv);
    Whi[idx] = (unsigned short)hi;
    Wlo[idx] = (unsigned short)f2b(wv - b2f_(hi));
}

// attribute-only occupancy control (launch_bounds overrides waves_per_eu -- R5/R6).
// waves_per_eu(2,2): 2 waves/SIMD -> 256-VGPR budget for ~200 live (Ahi 80 + acc 64 + ...).
__global__ __attribute__((amdgpu_flat_work_group_size(TPB, TPB)))
           __attribute__((amdgpu_waves_per_eu(2, 2)))
void k_lstm(
    const float* __restrict__ obs,
    const float* __restrict__ W_emb, const float* __restrict__ b_emb,
    const float* __restrict__ b_ih,  const float* __restrict__ b_hh,
    const unsigned short* __restrict__ Whi, const unsigned short* __restrict__ Wlo,
    const float* __restrict__ W_out, const float* __restrict__ b_out,
    float* __restrict__ out)
{
    __shared__ unsigned short Bbuf[4 * KT * 2 * 512];   // 20480 bf16 = 40 KB, frag-order
    __shared__ float h32[MROWS * H32S];                 // fp32 h for readout, 33.3 KB
    __shared__ float wout[2 * HH];
    __shared__ float wemb[EE * 2];
    __shared__ float bemb[EE];

    const int t    = threadIdx.x;
    const int lane = t & 63;
    const int w    = t >> 6;       // wave 0..7: gate-col tiles JT = 4w..4w+3
    const int q    = lane >> 4;    // 0..3
    const int cc   = lane & 15;
    const int row0 = blockIdx.x * MROWS;

    if (t < 2 * HH) wout[t] = W_out[t];
    if (t < EE * 2) wemb[t] = W_emb[t];
    if (t < EE)     bemb[t] = b_emb[t];
    for (int i = t; i < 4 * KT * 512; i += TPB) ((unsigned int*)Bbuf)[i] = 0;   // 10240 dwords
    for (int i = t; i < MROWS * H32S; i += TPB) h32[i] = 0.f;

    // A-hi fragments: registers for the whole kernel (20 frags = 80 VGPRs)
    s16x8 Ahi[KT][4];
#pragma unroll
    for (int kt = 0; kt < KT; kt++)
#pragma unroll
        for (int mt = 0; mt < 4; mt++)
            Ahi[kt][mt] = *(const s16x8*)(Whi + ((size_t)((w * 4 + mt) * KT + kt)) * 512 + lane * 8);

    f32x4 bias4[4];
#pragma unroll
    for (int mt = 0; mt < 4; mt++)
#pragma unroll
        for (int r = 0; r < 4; r++) {
            int jg  = (w * 4 + mt) * 16 + q * 4 + r;
            int col = (jg & 3) * HH + (jg >> 2);
            bias4[mt][r] = b_ih[col] + b_hh[col];
        }
    const float bo0 = b_out[0], bo1 = b_out[1];

    const int rrow = t >> 3;       // 0..63 (readout/embed row)
    const int rp   = t & 7;        // 8 partials / 8 embed-pairs
    const int grow = row0 + rrow;
    float pl0 = 0.f, pl1 = 0.f;

    float c16[4][4];
#pragma unroll
    for (int mt = 0; mt < 4; mt++)
#pragma unroll
        for (int nt = 0; nt < 4; nt++) c16[mt][nt] = 0.f;

    __syncthreads();

    // initial embed: x for step 0 (thread = (rrow, rp), 2 e's each)
    {
        float d0 = obs[(size_t)1 * BB * 2 + grow * 2 + 0] - obs[(size_t)0 * BB * 2 + grow * 2 + 0];
        float d1 = obs[(size_t)1 * BB * 2 + grow * 2 + 1] - obs[(size_t)0 * BB * 2 + grow * 2 + 1];
        int e0 = rp * 2;
        float v0 = bemb[e0]     + d0 * wemb[2 * e0]     + d1 * wemb[2 * e0 + 1]; v0 = v0 > 0.f ? v0 : 0.f;
        float v1 = bemb[e0 + 1] + d0 * wemb[2 * e0 + 2] + d1 * wemb[2 * e0 + 3]; v1 = v1 > 0.f ? v1 : 0.f;
        unsigned int h0 = f2b(v0), h1 = f2b(v1);
        unsigned int l0 = f2b(v0 - b2f_(h0)), l1 = f2b(v1 - b2f_(h1));
        int kg = rp >> 2, nt = rrow >> 4;
        int dw = (kg * 16 + (rrow & 15)) * 4 + (rp & 3);
        ((unsigned int*)Bbuf)[(FBX(nt, 0, 0) >> 1) + dw] = h0 | (h1 << 16);
        ((unsigned int*)Bbuf)[(FBX(nt, 0, 1) >> 1) + dw] = l0 | (l1 << 16);
    }
    __syncthreads();

#pragma unroll 1
    for (int s = 0; s < NSTEP; s++) {
        // ---- gates GEMM: 64 cols x 64 rows per wave, 3-term bf16 split ----
        f32x4 acc[4][4];
#pragma unroll
        for (int mt = 0; mt < 4; mt++)
#pragma unroll
            for (int nt = 0; nt < 4; nt++) acc[mt][nt] = bias4[mt];

#pragma unroll
        for (int kt = 0; kt < KT; kt++) {
            s16x8 al[4];
#pragma unroll
            for (int mt = 0; mt < 4; mt++)
                al[mt] = *(const s16x8*)(Wlo + ((size_t)((w * 4 + mt) * KT + kt)) * 512 + lane * 8);
#pragma unroll
            for (int nt = 0; nt < 4; nt++) {
                s16x8 bH = *(const s16x8*)&Bbuf[FBX(nt, kt, 0) + lane * 8];
#pragma unroll
                for (int mt = 0; mt < 4; mt++)
                    acc[mt][nt] = __builtin_amdgcn_mfma_f32_16x16x32_bf16(Ahi[kt][mt], bH, acc[mt][nt], 0, 0, 0);
#pragma unroll
                for (int mt = 0; mt < 4; mt++)
                    acc[mt][nt] = __builtin_amdgcn_mfma_f32_16x16x32_bf16(al[mt], bH, acc[mt][nt], 0, 0, 0);
                s16x8 bL = *(const s16x8*)&Bbuf[FBX(nt, kt, 1) + lane * 8];
#pragma unroll
                for (int mt = 0; mt < 4; mt++)
                    acc[mt][nt] = __builtin_amdgcn_mfma_f32_16x16x32_bf16(Ahi[kt][mt], bL, acc[mt][nt], 0, 0, 0);
            }
        }

        // ---- cell update: lane reg r = gate r of hidden j -- register-only ----
        float hn[4][4];
#pragma unroll
        for (int mt = 0; mt < 4; mt++)
#pragma unroll
            for (int nt = 0; nt < 4; nt++) {
                f32x4 g = acc[mt][nt];
                float cn = sigm(g[1]) * c16[mt][nt] + sigm(g[0]) * ftanh(g[2]);
                c16[mt][nt] = cn;
                hn[mt][nt] = sigm(g[3]) * ftanh(cn);
            }

        __syncthreads();   // B_A: all waves finished reading Bbuf this step

        // ---- h writeback: fp32 to h32, hi/lo pairs packed b32 into frag-order Bbuf ----
#pragma unroll
        for (int mt = 0; mt < 4; mt++) {
            int j0  = (w * 4 + mt) * 4;     // this lane's j = j0 + q
            int k   = EE + j0 + q;
            int kt_ = k >> 5, kg = (k >> 3) & 3, e = k & 7;
#pragma unroll
            for (int nt = 0; nt < 4; nt++) {
                int row = nt * 16 + cc;
                float h = hn[mt][nt];
                h32[row * H32S + j0 + q] = h;
                unsigned int hu = f2b(h);
                unsigned int lu = f2b(h - b2f_(hu));
                unsigned int hup = __shfl_xor(hu, 16, 64);   // partner q^1 holds j0+q^1
                unsigned int lup = __shfl_xor(lu, 16, 64);
                if (!(q & 1)) {                              // q = 0,2 write packed pairs
                    int dw = (kg * 16 + cc) * 4 + (e >> 1);
                    ((unsigned int*)Bbuf)[(FBX(nt, kt_, 0) >> 1) + dw] = hu | (hup << 16);
                    ((unsigned int*)Bbuf)[(FBX(nt, kt_, 1) >> 1) + dw] = lu | (lup << 16);
                }
            }
        }

        __syncthreads();   // B_B: h visible

        // ---- readout (fp32 h), position update, next-step embed ----
        {
            float r0 = 0.f, r1 = 0.f;
            const float* hp = &h32[rrow * H32S + rp * 16];
#pragma unroll
            for (int m4 = 0; m4 < 4; m4++) {
                float4 hv = *(const float4*)(hp + m4 * 4);
                float4 w0 = *(const float4*)&wout[rp * 16 + m4 * 4];
                float4 w1 = *(const float4*)&wout[HH + rp * 16 + m4 * 4];
                r0 += hv.x * w0.x + hv.y * w0.y + hv.z * w0.z + hv.w * w0.w;
                r1 += hv.x * w1.x + hv.y * w1.y + hv.z * w1.z + hv.w * w1.w;
            }
#pragma unroll
            for (int m = 1; m < 8; m <<= 1) {
                r0 += __shfl_xor(r0, m, 64);
                r1 += __shfl_xor(r1, m, 64);
            }
            float base0, base1;
            if (s < OBS) {
                base0 = obs[(size_t)(s + 1) * BB * 2 + grow * 2 + 0];
                base1 = obs[(size_t)(s + 1) * BB * 2 + grow * 2 + 1];
            } else { base0 = pl0; base1 = pl1; }
            float pos0 = base0 + r0 + bo0;
            float pos1 = base1 + r1 + bo1;
            if (rp == 0) {
                out[((size_t)s * BB + grow) * 2 + 0] = pos0;
                out[((size_t)s * BB + grow) * 2 + 1] = pos1;
            }
            if (s + 1 < NSTEP) {
                float d0, d1;
                if (s + 1 < OBS) {
                    d0 = obs[(size_t)(s + 2) * BB * 2 + grow * 2 + 0] - obs[(size_t)(s + 1) * BB * 2 + grow * 2 + 0];
                    d1 = obs[(size_t)(s + 2) * BB * 2 + grow * 2 + 1] - obs[(size_t)(s + 1) * BB * 2 + grow * 2 + 1];
                } else { d0 = pos0 - pl0; d1 = pos1 - pl1; }
                int e0 = rp * 2;
                float v0 = bemb[e0]     + d0 * wemb[2 * e0]     + d1 * wemb[2 * e0 + 1]; v0 = v0 > 0.f ? v0 : 0.f;
                float v1 = bemb[e0 + 1] + d0 * wemb[2 * e0 + 2] + d1 * wemb[2 * e0 + 3]; v1 = v1 > 0.f ? v1 : 0.f;
                unsigned int h0 = f2b(v0), h1 = f2b(v1);
                unsigned int l0 = f2b(v0 - b2f_(h0)), l1 = f2b(v1 - b2f_(h1));
                int kg = rp >> 2, nt = rrow >> 4;
                int dw = (kg * 16 + (rrow & 15)) * 4 + (rp & 3);
                ((unsigned int*)Bbuf)[(FBX(nt, 0, 0) >> 1) + dw] = h0 | (h1 << 16);
                ((unsigned int*)Bbuf)[(FBX(nt, 0, 1) >> 1) + dw] = l0 | (l1 << 16);
            }
            pl0 = pos0; pl1 = pos1;
        }
        __syncthreads();   // B_C: x[s+1] sealed before next GEMM
    }
}

extern "C" void kernel_launch(void* const* d_in, const int* in_sizes, int n_in,
                              void* d_out, int out_size, void* d_ws, size_t ws_size,
                              hipStream_t stream)
{
    const float* obs   = (const float*)d_in[0];
    const float* W_emb = (const float*)d_in[1];
    const float* b_emb = (const float*)d_in[2];
    const float* W_ih  = (const float*)d_in[3];
    const float* b_ih  = (const float*)d_in[4];
    const float* W_hh  = (const float*)d_in[5];
    const float* b_hh  = (const float*)d_in[6];
    const float* W_out = (const float*)d_in[7];
    const float* b_out = (const float*)d_in[8];
    float* out = (float*)d_out;

    unsigned short* Whi = (unsigned short*)d_ws;        // 81920 bf16
    unsigned short* Wlo = Whi + 32 * KT * 512;          // 81920 bf16

    hipLaunchKernelGGL(k_prep, dim3(32 * KT * 512 / 256), dim3(256), 0, stream,
                       W_ih, W_hh, Whi, Wlo);

    hipLaunchKernelGGL(k_lstm, dim3(BB / MROWS), dim3(TPB), 0, stream,
                       obs, W_emb, b_emb, b_ih, b_hh, Whi, Wlo, W_out, b_out, out);
}